// Round 6
// baseline (1305.415 us; speedup 1.0000x reference)
//
#include <hip/hip_runtime.h>

// HMM forward (CgpHmmCell): B=512, T=4096, S=64, M=125.
// Round 23: R18 + ALIGNED-UNIT LOADS + BYTE-SCATTER EXTRACTION.
// Post-mortems R19-R22: every structural rearrangement (depth-4, kernel
// split, temporal phases, producer/consumer waves) lands at the same ~275us
// -> the extraction stream ITSELF runs at ~3.9 TB/s (62% of achievable) and
// nothing else matters. Suspect: lane loads 16B at byte 500r+16rel; 500%16=4
// -> 75% of rows give 4B-aligned dwordx4, which the TA splits into multiple
// micro-ops -> VMEM pipeline throttles at ~2-4x per-instruction cost.
// Fix: 8 rows = 4000 B = exactly 250 aligned 16B chunks, and every 8-row
// unit in the schedule starts at row%8==0 -> unit base 16B-aligned. Load
// units as 250 aligned vec4s (4/lane, tail clamps to chunk 249 = benign
// same-value duplicates). Extract by bit-test ((u>>29)&1 etc: values are
// exactly 0x0/0x3F800000), d = 4c+ctz, row = d*8389>>20 (exact for d<1000),
// o = d-125row, ds_write_b8 straight into the myu u64 slot (byte b = row b
// matches old layout; <=2 hits/chunk handled; same-wave LDS ordering).
// Deposit map (incl. K/L duals + wq==0 clamp-to-0) identical to R18 ->
// absmax 0.0. Ping-pong bufP/bufQ distance-2, Phase A 17 groups, scan math,
// 2^56 rescale, mass identity, chunk-0 override: all byte-identical R18.

#define BATCH 512
#define T 4096
#define S 64
#define M 125
#define BMS 68     // BmL row stride in dwords: 68%32=4 -> 8 bank phases, 16B-aligned
#define NPACK 10   // 2 burn + 8 accumulate (chunk = 64 steps)
#define BURNP 2
#define WPB 4
#define RB 56.0f
#define SCALEF 7.205759403792794e16f   // 2^56

typedef __attribute__((ext_vector_type(8))) short bf16x8;
typedef __attribute__((ext_vector_type(4))) float f32x4;

union BFU { unsigned u[4]; bf16x8 v; };

__device__ __forceinline__ unsigned pk_trunc(float a, float b) {
    return (__float_as_uint(b) & 0xFFFF0000u) | (__float_as_uint(a) >> 16);
}
__device__ __forceinline__ unsigned pk_rne(float a, float b) {
    unsigned ua = __float_as_uint(a); ua += 0x7FFFu + ((ua >> 16) & 1u);
    unsigned ub = __float_as_uint(b); ub += 0x7FFFu + ((ub >> 16) & 1u);
    return (ub & 0xFFFF0000u) | (ua >> 16);
}

__global__ __launch_bounds__(256) void hmm_fused(const float* __restrict__ x,
                                                 const float* __restrict__ Iv,
                                                 const float* __restrict__ A,
                                                 const float* __restrict__ Bm,
                                                 float* __restrict__ out) {
    __shared__ __align__(16) float BmL[M * BMS];               // 34000 B
    __shared__ __align__(16) float ILds[S];
    __shared__ unsigned long long ulds[WPB * 16 * NPACK];      // 5120 B

    const int tid = threadIdx.x, wv = tid >> 6, lane = tid & 63;
    const int s = lane & 15, g = lane >> 4;

    for (int i = tid; i < M * S; i += WPB * 64)
        BmL[(i >> 6) * BMS + (i & 63)] = Bm[i];
    if (tid < S) ILds[tid] = Iv[tid];
    __syncthreads();

    // A^T fragments under pi: slot (kf,g,j2,e) holds A[p0+e][16mt+s],
    // p0 = 32kf + 16*(j2>>1) + 4g + 2*(j2&1).
    BFU Af[4][2];
#pragma unroll
    for (int mt = 0; mt < 4; ++mt)
#pragma unroll
        for (int kf = 0; kf < 2; ++kf)
#pragma unroll
            for (int j2 = 0; j2 < 4; ++j2) {
                int p0 = 32 * kf + 16 * (j2 >> 1) + 4 * g + 2 * (j2 & 1);
                Af[mt][kf].u[j2] = pk_rne(A[(size_t)p0 * S + mt * 16 + s],
                                          A[(size_t)(p0 + 1) * S + mt * 16 + s]);
            }

    const int W = blockIdx.x * WPB + wv;   // 0..2047
    const int seq = W >> 2, wq = W & 3;    // 4 waves per sequence
    const float* xs = x + (size_t)seq * T * M;
    unsigned long long* myu = &ulds[wv * 16 * NPACK];
    unsigned char* mb = (unsigned char*)myu;   // LDS byte view of my slots
    const int base = wq * 1024;            // wave's first row (seq-relative)

    f32x4 bufP[8], bufQ[8];                // ping-pong: 2 x (2 units) in flight

    // Load one 8-row unit (4000 B = 250 aligned vec4s) per buffer half.
    // Unit first row r0 is always %8==0 -> byte base 500*r0 is 16B-aligned.
    auto issueU = [&](f32x4 (&bf)[8], int r0a, int r0b) {
#pragma unroll
        for (int j = 0; j < 4; ++j) {
            unsigned c = (j == 3)
                ? ((unsigned)lane + 192u > 249u ? 249u : (unsigned)lane + 192u)
                : (unsigned)(lane + 64 * j);
            bf[j]     = *(const f32x4*)&xs[125u * (unsigned)r0a + 4u * c];
            bf[4 + j] = *(const f32x4*)&xs[125u * (unsigned)r0b + 4u * c];
        }
    };
    // Extract the 8 o-bytes of one unit and byte-scatter them into slot
    // byte-offset ad0 (and ad1 if >=0). Values are exactly 0x0/0x3F800000.
    auto extdep = [&](const f32x4 (&bf)[8], int half, int ad0, int ad1) {
#pragma unroll
        for (int j = 0; j < 4; ++j) {
            f32x4 v = bf[half * 4 + j];
            unsigned m = ((__float_as_uint(v.x) >> 29) & 1u) |
                         ((__float_as_uint(v.y) >> 28) & 2u) |
                         ((__float_as_uint(v.z) >> 27) & 4u) |
                         ((__float_as_uint(v.w) >> 26) & 8u);
            if (m) {
                unsigned c = (j == 3)
                    ? ((unsigned)lane + 192u > 249u ? 249u : (unsigned)lane + 192u)
                    : (unsigned)(lane + 64 * j);
                unsigned d = 4u * c + (unsigned)__builtin_ctz(m);
                unsigned rr = (d * 8389u) >> 20;       // floor(d/125), d<1000
                unsigned o = d - 125u * rr;
                mb[ad0 + rr] = (unsigned char)o;
                if (ad1 >= 0) mb[ad1 + rr] = (unsigned char)o;
                unsigned m2 = m & (m - 1u);            // row-straddle 2nd hit
                if (m2) {
                    unsigned d2 = 4u * c + (unsigned)__builtin_ctz(m2);
                    unsigned rr2 = (d2 * 8389u) >> 20;
                    unsigned o2 = d2 - 125u * rr2;
                    mb[ad0 + rr2] = (unsigned char)o2;
                    if (ad1 >= 0) mb[ad1 + rr2] = (unsigned char)o2;
                }
            }
        }
    };
    auto depaddr = [&](int st, int pt) { return 8 * (st * NPACK + pt); };

    // ---- Phase A: PRE (boundary burn) + K (rel 48..56) + L (rel 56..64) ----
    {
        int pa = base - 16, pb = base - 8;
        if (pa < 0) pa = 0;                // wq==0: rows 0..7 twice (R18 clamp)
        if (pb < 0) pb = 0;
        issueU(bufP, pa, pb);
        for (int gi = 0; gi <= 16; ++gi) {
            int a00, a01, a10, a11;
            if (gi == 0) {                                   // PRE -> (0,p0),(0,p1)
                a00 = depaddr(0, 0); a01 = -1;
                a10 = depaddr(0, 1); a11 = -1;
            } else if (gi <= 8) {                            // K: (c,p8) & (c+1,p0)
                int i = gi - 1;
                a00 = depaddr(2 * i, 8);     a01 = depaddr(2 * i + 1, 0);
                a10 = depaddr(2 * i + 1, 8); a11 = (2 * i + 2 <= 15) ? depaddr(2 * i + 2, 0) : -1;
            } else {                                         // L: (c,p9) & (c+1,p1)
                int i = gi - 9;
                a00 = depaddr(2 * i, 9);     a01 = depaddr(2 * i + 1, 1);
                a10 = depaddr(2 * i + 1, 9); a11 = (2 * i + 2 <= 15) ? depaddr(2 * i + 2, 1) : -1;
            }
            extdep(bufP, 0, a00, a01);
            extdep(bufP, 1, a10, a11);
            if (gi < 16) {                                   // issue next group
                int ni = gi + 1;
                if (ni <= 8) { int i = ni - 1; issueU(bufP, base + 128 * i + 48, base + 128 * i + 112); }
                else         { int i = ni - 9; issueU(bufP, base + 128 * i + 56, base + 128 * i + 120); }
            } else {
                issueU(bufP, base + 0, base + 64);           // step 0 (p0,k0)
            }
        }
        issueU(bufQ, base + 128, base + 192);                // step 1 (p0,k1)
    }

    // ---- Phase B: scan packs 0..9; packs 0..5 interleave extraction ----
    BFU Bf[2];
#pragma unroll
    for (int kf = 0; kf < 2; ++kf)
#pragma unroll
        for (int j = 0; j < 4; ++j) Bf[kf].u[j] = 0x3F803F80u;  // 1.0 burn seed

    float S0v = 0.f, swv = 1.f;

    for (int p = 0; p < NPACK; ++p) {
        unsigned long long uv = myu[s * NPACK + p];   // this pack's o-bytes
        const bool exsl = (p < 6);
#pragma unroll
        for (int k = 0; k < 8; ++k) {
            // --- MFMA section first (issue, don't consume yet) ---
            const int o = (int)(uv & 255ull);
            uv >>= 8;
            const float* br = &BmL[o * BMS];          // per-stream row, bank-phased
            f32x4 E[4], z0[4], z1[4];
#pragma unroll
            for (int mt = 0; mt < 4; ++mt) {
                E[mt] = *(const f32x4*)&br[mt * 16 + g * 4];
                f32x4 zr = {0.f, 0.f, 0.f, 0.f};
                z0[mt] = __builtin_amdgcn_mfma_f32_16x16x32_bf16(Af[mt][0].v, Bf[0].v, zr, 0, 0, 0);
                z1[mt] = __builtin_amdgcn_mfma_f32_16x16x32_bf16(Af[mt][1].v, Bf[1].v, zr, 0, 0, 0);
            }
            // --- extraction (vmcnt wait overlaps MFMAs); distance-2 refill ---
            if (exsl) {
                const int ad0 = 8 * ((2 * k) * NPACK + (p + 2));
                const int ad1 = 8 * ((2 * k + 1) * NPACK + (p + 2));
                // k is compile-time (unrolled): buffer parity = k&1
                if ((k & 1) == 0) { extdep(bufP, 0, ad0, -1); extdep(bufP, 1, ad1, -1); }
                else              { extdep(bufQ, 0, ad0, -1); extdep(bufQ, 1, ad1, -1); }
                int k2 = k + 2, p2 = p;
                bool ok = true;
                if (k2 >= 8) { k2 -= 8; p2 = p + 1; ok = (p2 < 6); }
                if (ok) {
                    int r0a = base + (2 * k2) * 64 + 8 * p2;
                    if ((k & 1) == 0) issueU(bufP, r0a, r0a + 64);
                    else              issueU(bufQ, r0a, r0a + 64);
                }
            }
            // --- consume MFMA results ---
            float w[4][4];
#pragma unroll
            for (int mt = 0; mt < 4; ++mt)
#pragma unroll
                for (int r = 0; r < 4; ++r) w[mt][r] = (z0[mt][r] + z1[mt][r]) * E[mt][r];
            if (p == BURNP && k == 0 && wq == 0) {    // exact t=0 init of chunk 0
                const bool c0 = (s == 0);
#pragma unroll
                for (int mt = 0; mt < 4; ++mt)
#pragma unroll
                    for (int r = 0; r < 4; ++r)
                        w[mt][r] = c0 ? ILds[mt * 16 + g * 4 + r] * E[mt][r] : w[mt][r];
            }
            if (k == 7 && (p == BURNP - 1 || p == NPACK - 1)) {  // mass (pre-scale)
                float swl = 0.f;
#pragma unroll
                for (int mt = 0; mt < 4; ++mt)
#pragma unroll
                    for (int r = 0; r < 4; ++r) swl += w[mt][r];
                swl += __shfl_xor(swl, 16);
                swl += __shfl_xor(swl, 32);
                swv = swl;
            }
            // zero-shuffle C->B under pi; constant 2^56 rescale at k==7
#pragma unroll
            for (int kf = 0; kf < 2; ++kf)
#pragma unroll
                for (int j2 = 0; j2 < 4; ++j2) {
                    int mt = 2 * kf + (j2 >> 1), pr = j2 & 1;
                    float v0 = w[mt][2 * pr], v1 = w[mt][2 * pr + 1];
                    if (k == 7) { v0 *= SCALEF; v1 *= SCALEF; }
                    Bf[kf].u[j2] = pk_trunc(v0, v1);
                }
        }
        if (p == BURNP - 1) {
            // exponents: burn mass carries 1*RB, final carries (NPACK-1)*RB
            const bool ch0 = (wq == 0) && (s == 0);
            S0v = ch0 ? ((float)(NPACK - 1 - BURNP) * RB)
                      : (__log2f(swv) + (float)(NPACK - BURNP) * RB);
        }
    }

    float tot = __log2f(swv) - S0v;
    // sum over the 16 streams (s-dim); g-lanes hold duplicates
    tot += __shfl_xor(tot, 1);
    tot += __shfl_xor(tot, 2);
    tot += __shfl_xor(tot, 4);
    tot += __shfl_xor(tot, 8);
    if (lane == 0)
        atomicAdd(out + seq, tot * 0.6931471805599453f);
}

extern "C" void kernel_launch(void* const* d_in, const int* in_sizes, int n_in,
                              void* d_out, int out_size, void* d_ws, size_t ws_size,
                              hipStream_t stream) {
    const float* x  = (const float*)d_in[0];   // [B,T,M] one-hot
    const float* I  = (const float*)d_in[1];   // [1,S]
    const float* A  = (const float*)d_in[2];   // [S,S]
    const float* Bm = (const float*)d_in[3];   // [M,S]
    float* out = (float*)d_out;                // [B,1]
    (void)d_ws; (void)ws_size;                 // workspace unused (fully fused)

    hipMemsetAsync(out, 0, (size_t)out_size * sizeof(float), stream);
    hmm_fused<<<(BATCH * 4) / WPB, WPB * 64, 0, stream>>>(x, I, A, Bm, out);  // 2048 waves
}